// Round 3
// baseline (512.654 us; speedup 1.0000x reference)
//
#include <hip/hip_runtime.h>
#include <math.h>

#define IN_CH 256
#define OUT_CH 64

// ---------------------------------------------------------------------------
// deg[n] = 1 (self loop) + #edges with dst == n
// ---------------------------------------------------------------------------
__global__ void k_init_deg(float* __restrict__ deg, int N) {
    int i = blockIdx.x * blockDim.x + threadIdx.x;
    int stride = gridDim.x * blockDim.x;
    for (; i < N; i += stride) deg[i] = 1.0f;
}

__global__ void k_count_deg(const int* __restrict__ dst, float* __restrict__ deg, int E) {
    int i = blockIdx.x * blockDim.x + threadIdx.x;
    int stride = gridDim.x * blockDim.x;
    for (; i < E; i += stride) atomicAdd(&deg[dst[i]], 1.0f);
}

// ---------------------------------------------------------------------------
// h = x @ W;  g = h * dinv[row];  acc = g  (self-loop contribution pre-seeded)
// Block: 512 threads, 64 rows/block, 8 threads per row each owning 8 channels.
// W (256x64 f32 = 64KB) staged in LDS; reads are 8-way broadcast b128.
// ---------------------------------------------------------------------------
__global__ __launch_bounds__(512) void k_gemm_scale(
    const float* __restrict__ x, const float* __restrict__ W,
    const float* __restrict__ deg, float* __restrict__ g,
    float* __restrict__ acc, int N)
{
    __shared__ float Wlds[IN_CH * OUT_CH];  // 64 KB
    const int tid = threadIdx.x;
    for (int i = tid * 4; i < IN_CH * OUT_CH; i += 512 * 4) {
        *(float4*)&Wlds[i] = *(const float4*)&W[i];
    }
    __syncthreads();

    const int row = blockIdx.x * 64 + (tid >> 3);
    if (row >= N) return;
    const int cg = (tid & 7) * 8;  // channel group start

    float a[8] = {0.f, 0.f, 0.f, 0.f, 0.f, 0.f, 0.f, 0.f};
    const float* __restrict__ xr = x + (size_t)row * IN_CH;

    for (int k = 0; k < IN_CH; k += 4) {
        const float4 xv = *(const float4*)&xr[k];
        const float xs[4] = {xv.x, xv.y, xv.z, xv.w};
#pragma unroll
        for (int kk = 0; kk < 4; ++kk) {
            const float4 w0 = *(const float4*)&Wlds[(k + kk) * OUT_CH + cg];
            const float4 w1 = *(const float4*)&Wlds[(k + kk) * OUT_CH + cg + 4];
            a[0] += xs[kk] * w0.x; a[1] += xs[kk] * w0.y;
            a[2] += xs[kk] * w0.z; a[3] += xs[kk] * w0.w;
            a[4] += xs[kk] * w1.x; a[5] += xs[kk] * w1.y;
            a[6] += xs[kk] * w1.z; a[7] += xs[kk] * w1.w;
        }
    }

    const float dinv = rsqrtf(deg[row]);
    const float4 r0 = make_float4(a[0] * dinv, a[1] * dinv, a[2] * dinv, a[3] * dinv);
    const float4 r1 = make_float4(a[4] * dinv, a[5] * dinv, a[6] * dinv, a[7] * dinv);
    const size_t o = (size_t)row * OUT_CH + cg;
    *(float4*)&g[o]       = r0;
    *(float4*)&g[o + 4]   = r1;
    *(float4*)&acc[o]     = r0;
    *(float4*)&acc[o + 4] = r1;
}

// ---------------------------------------------------------------------------
// acc[dst] += g[src] for each edge. One wave per edge, lane = channel.
// ---------------------------------------------------------------------------
__global__ void k_scatter(const int* __restrict__ src, const int* __restrict__ dst,
                          const float* __restrict__ g, float* __restrict__ acc, int E)
{
    const int lane = threadIdx.x & 63;
    int wid = (blockIdx.x * blockDim.x + threadIdx.x) >> 6;
    const int nw = (gridDim.x * blockDim.x) >> 6;
    for (int e = wid; e < E; e += nw) {
        const int s = src[e];
        const int d = dst[e];
        const float v = g[(size_t)s * OUT_CH + lane];
        atomicAdd(&acc[(size_t)d * OUT_CH + lane], v);
    }
}

// ---------------------------------------------------------------------------
// z = acc * dinv + b; out = z - logsumexp(z). One wave per node, lane = channel.
// In-place safe: each wave reads/writes only its own row.
// ---------------------------------------------------------------------------
__global__ void k_logsoftmax(const float* __restrict__ acc, const float* __restrict__ deg,
                             const float* __restrict__ b, float* __restrict__ out, int N)
{
    const int lane = threadIdx.x & 63;
    int wid = (blockIdx.x * blockDim.x + threadIdx.x) >> 6;
    const int nw = (gridDim.x * blockDim.x) >> 6;
    const float bc = b[lane];
    for (int i = wid; i < N; i += nw) {
        const float dinv = rsqrtf(deg[i]);
        const float z = acc[(size_t)i * OUT_CH + lane] * dinv + bc;
        float m = z;
#pragma unroll
        for (int off = 32; off; off >>= 1) m = fmaxf(m, __shfl_xor(m, off));
        float e = __expf(z - m);
        float s = e;
#pragma unroll
        for (int off = 32; off; off >>= 1) s += __shfl_xor(s, off);
        out[(size_t)i * OUT_CH + lane] = z - m - __logf(s);
    }
}

// ---------------------------------------------------------------------------
extern "C" void kernel_launch(void* const* d_in, const int* in_sizes, int n_in,
                              void* d_out, int out_size, void* d_ws, size_t ws_size,
                              hipStream_t stream) {
    const float* x  = (const float*)d_in[0];
    const int*   ei = (const int*)d_in[1];
    const float* W  = (const float*)d_in[2];
    const float* b  = (const float*)d_in[3];
    float* out = (float*)d_out;

    const int N = in_sizes[0] / IN_CH;  // 100000
    const int E = in_sizes[1] / 2;      // 1600000
    const int* src = ei;
    const int* dst = ei + E;

    // workspace layout: deg[N] | g[N*64]   (~26 MB); accumulate into d_out.
    const size_t degBytes = (((size_t)N * sizeof(float)) + 255) & ~(size_t)255;
    float* deg = (float*)d_ws;
    float* g   = (float*)((char*)d_ws + degBytes);
    float* acc = out;  // accumulate directly into output, log_softmax in place

    k_init_deg  <<<512, 256, 0, stream>>>(deg, N);
    k_count_deg <<<2048, 256, 0, stream>>>(dst, deg, E);
    k_gemm_scale<<<(N + 63) / 64, 512, 0, stream>>>(x, W, deg, g, acc, N);
    k_scatter   <<<4096, 256, 0, stream>>>(src, dst, g, acc, E);
    k_logsoftmax<<<2048, 256, 0, stream>>>(acc, deg, b, out, N);
}

// Round 4
// 380.344 us; speedup vs baseline: 1.3479x; 1.3479x over previous
//
#include <hip/hip_runtime.h>
#include <math.h>

#define IN_CH 256
#define OUT_CH 64
#define SCAN_BS 256
#define SCAN_ITEMS 4
#define SCAN_TILE (SCAN_BS * SCAN_ITEMS)  // 1024

// ---------------------------------------------------------------------------
__global__ void k_zero(int* __restrict__ p, int n) {
    int i = blockIdx.x * blockDim.x + threadIdx.x;
    int stride = gridDim.x * blockDim.x;
    for (; i < n; i += stride) p[i] = 0;
}

// cnt[d] = # edges with dst == d
__global__ void k_count(const int* __restrict__ dst, int* __restrict__ cnt, int E) {
    int i = blockIdx.x * blockDim.x + threadIdx.x;
    int stride = gridDim.x * blockDim.x;
    for (; i < E; i += stride) atomicAdd(&cnt[dst[i]], 1);
}

// ---------------------------------------------------------------------------
// Exclusive scan of cnt[0..N) -> offs[0..N]; also cursor[i] = offs[i].
// ---------------------------------------------------------------------------
__global__ void k_scan1(const int* __restrict__ cnt, int* __restrict__ partials, int N) {
    __shared__ int sdata[SCAN_BS];
    const int t = threadIdx.x;
    const int base = blockIdx.x * SCAN_TILE + t * SCAN_ITEMS;
    int s = 0;
#pragma unroll
    for (int j = 0; j < SCAN_ITEMS; ++j) {
        int i = base + j;
        if (i < N) s += cnt[i];
    }
    sdata[t] = s;
    __syncthreads();
    for (int off = SCAN_BS / 2; off > 0; off >>= 1) {
        if (t < off) sdata[t] += sdata[t + off];
        __syncthreads();
    }
    if (t == 0) partials[blockIdx.x] = sdata[0];
}

__global__ void k_scan2(int* __restrict__ partials, int NB) {  // 1 block, 1024 thr
    __shared__ int sdata[1024];
    const int t = threadIdx.x;
    const int orig = (t < NB) ? partials[t] : 0;
    sdata[t] = orig;
    __syncthreads();
    for (int off = 1; off < 1024; off <<= 1) {
        int v = (t >= off) ? sdata[t - off] : 0;
        __syncthreads();
        sdata[t] += v;
        __syncthreads();
    }
    if (t < NB) partials[t] = sdata[t] - orig;  // exclusive
}

__global__ void k_scan3(const int* __restrict__ cnt, const int* __restrict__ partials,
                        int* __restrict__ offs, int* __restrict__ cursor, int N) {
    __shared__ int sdata[SCAN_BS];
    const int t = threadIdx.x;
    const int base = blockIdx.x * SCAN_TILE + t * SCAN_ITEMS;
    int v[SCAN_ITEMS];
    int s = 0;
#pragma unroll
    for (int j = 0; j < SCAN_ITEMS; ++j) {
        int i = base + j;
        v[j] = (i < N) ? cnt[i] : 0;
        s += v[j];
    }
    sdata[t] = s;
    __syncthreads();
    for (int off = 1; off < SCAN_BS; off <<= 1) {
        int u = (t >= off) ? sdata[t - off] : 0;
        __syncthreads();
        sdata[t] += u;
        __syncthreads();
    }
    int run = partials[blockIdx.x] + sdata[t] - s;  // exclusive prefix for this thread
#pragma unroll
    for (int j = 0; j < SCAN_ITEMS; ++j) {
        int i = base + j;
        if (i < N) {
            offs[i] = run;
            cursor[i] = run;
            run += v[j];
            if (i == N - 1) offs[N] = run;
        }
    }
}

// ---------------------------------------------------------------------------
// list[pos] = src for each edge, bucketed by dst (counting sort fill).
// ---------------------------------------------------------------------------
__global__ void k_fill(const int* __restrict__ src, const int* __restrict__ dst,
                       int* __restrict__ cursor, int* __restrict__ list, int E) {
    int i = blockIdx.x * blockDim.x + threadIdx.x;
    int stride = gridDim.x * blockDim.x;
    for (; i < E; i += stride) {
        int p = atomicAdd(&cursor[dst[i]], 1);
        list[p] = src[i];
    }
}

// ---------------------------------------------------------------------------
// g = (x @ W) * dinv[row].  512 thr: 64 rows/block, 8 thr/row x 8 ch.
// ---------------------------------------------------------------------------
__global__ __launch_bounds__(512) void k_gemm_scale(
    const float* __restrict__ x, const float* __restrict__ W,
    const int* __restrict__ cnt, float* __restrict__ g, int N)
{
    __shared__ float Wlds[IN_CH * OUT_CH];  // 64 KB
    const int tid = threadIdx.x;
    for (int i = tid * 4; i < IN_CH * OUT_CH; i += 512 * 4) {
        *(float4*)&Wlds[i] = *(const float4*)&W[i];
    }
    __syncthreads();

    const int row = blockIdx.x * 64 + (tid >> 3);
    if (row >= N) return;
    const int cg = (tid & 7) * 8;

    float a[8] = {0.f, 0.f, 0.f, 0.f, 0.f, 0.f, 0.f, 0.f};
    const float* __restrict__ xr = x + (size_t)row * IN_CH;

    for (int k = 0; k < IN_CH; k += 4) {
        const float4 xv = *(const float4*)&xr[k];
        const float xs[4] = {xv.x, xv.y, xv.z, xv.w};
#pragma unroll
        for (int kk = 0; kk < 4; ++kk) {
            const float4 w0 = *(const float4*)&Wlds[(k + kk) * OUT_CH + cg];
            const float4 w1 = *(const float4*)&Wlds[(k + kk) * OUT_CH + cg + 4];
            a[0] += xs[kk] * w0.x; a[1] += xs[kk] * w0.y;
            a[2] += xs[kk] * w0.z; a[3] += xs[kk] * w0.w;
            a[4] += xs[kk] * w1.x; a[5] += xs[kk] * w1.y;
            a[6] += xs[kk] * w1.z; a[7] += xs[kk] * w1.w;
        }
    }

    const float dinv = rsqrtf((float)(cnt[row] + 1));  // +1 self loop
    const size_t o = (size_t)row * OUT_CH + cg;
    *(float4*)&g[o]     = make_float4(a[0]*dinv, a[1]*dinv, a[2]*dinv, a[3]*dinv);
    *(float4*)&g[o + 4] = make_float4(a[4]*dinv, a[5]*dinv, a[6]*dinv, a[7]*dinv);
}

// ---------------------------------------------------------------------------
// One wave per node: acc = g[i] + sum_{s in list[offs[i]..offs[i+1])} g[s];
// z = acc*dinv_i + b; out = z - logsumexp(z).  lane = channel.
// ---------------------------------------------------------------------------
__global__ void k_aggregate(const int* __restrict__ offs, const int* __restrict__ list,
                            const float* __restrict__ g, const float* __restrict__ b,
                            float* __restrict__ out, int N)
{
    const int lane = threadIdx.x & 63;
    int wid = (blockIdx.x * blockDim.x + threadIdx.x) >> 6;
    const int nw = (gridDim.x * blockDim.x) >> 6;
    const float bc = b[lane];

    for (int i = wid; i < N; i += nw) {
        const int start = offs[i];
        const int end = offs[i + 1];
        float acc = g[(size_t)i * OUT_CH + lane];  // self loop

        for (int e0 = start; e0 < end; e0 += 64) {
            const int n = min(64, end - e0);
            const int idx = (lane < n) ? list[e0 + lane] : 0;
            for (int j = 0; j < n; ++j) {
                const int s = __shfl(idx, j);
                acc += g[(size_t)s * OUT_CH + lane];
            }
        }

        const float dinv = rsqrtf((float)(end - start + 1));
        const float z = acc * dinv + bc;

        float m = z;
#pragma unroll
        for (int off = 32; off; off >>= 1) m = fmaxf(m, __shfl_xor(m, off));
        float e = __expf(z - m);
        float s = e;
#pragma unroll
        for (int off = 32; off; off >>= 1) s += __shfl_xor(s, off);
        out[(size_t)i * OUT_CH + lane] = z - m - __logf(s);
    }
}

// ---------------------------------------------------------------------------
extern "C" void kernel_launch(void* const* d_in, const int* in_sizes, int n_in,
                              void* d_out, int out_size, void* d_ws, size_t ws_size,
                              hipStream_t stream) {
    const float* x  = (const float*)d_in[0];
    const int*   ei = (const int*)d_in[1];
    const float* W  = (const float*)d_in[2];
    const float* b  = (const float*)d_in[3];
    float* out = (float*)d_out;

    const int N = in_sizes[0] / IN_CH;  // 100000
    const int E = in_sizes[1] / 2;      // 1600000
    const int* src = ei;
    const int* dst = ei + E;

    const int NB = (N + SCAN_TILE - 1) / SCAN_TILE;  // 98

    // ws layout: cnt[N] | offs[N+1] | cursor[N] | partials[1024] | list[E] | g[N*64]
    char* p = (char*)d_ws;
    auto alloc = [&](size_t bytes) { char* q = p; p += (bytes + 255) & ~(size_t)255; return q; };
    int*   cnt      = (int*)alloc((size_t)N * 4);
    int*   offs     = (int*)alloc((size_t)(N + 1) * 4);
    int*   cursor   = (int*)alloc((size_t)N * 4);
    int*   partials = (int*)alloc(1024 * 4);
    int*   list     = (int*)alloc((size_t)E * 4);
    float* g        = (float*)alloc((size_t)N * OUT_CH * 4);

    k_zero      <<<256, 256, 0, stream>>>(cnt, N);
    k_count     <<<2048, 256, 0, stream>>>(dst, cnt, E);
    k_scan1     <<<NB, SCAN_BS, 0, stream>>>(cnt, partials, N);
    k_scan2     <<<1, 1024, 0, stream>>>(partials, NB);
    k_scan3     <<<NB, SCAN_BS, 0, stream>>>(cnt, partials, offs, cursor, N);
    k_gemm_scale<<<(N + 63) / 64, 512, 0, stream>>>(x, W, cnt, g, N);
    k_fill      <<<2048, 256, 0, stream>>>(src, dst, cursor, list, E);
    k_aggregate <<<4096, 256, 0, stream>>>(offs, list, g, b, out, N);
}